// Round 1
// baseline (4616.370 us; speedup 1.0000x reference)
//
#include <hip/hip_runtime.h>

#define T_LEN 2048
#define BSZ 16
#define NHEAD 8
#define HD 64
#define MF 266
#define SC 128
#define NSEG 16
#define NTHR 256
#define BH (BSZ*NHEAD)

constexpr float DN    = 0.3535533905932738f;    // 64^-0.25
constexpr float RATIO = 0.06131393394849658f;   // 266^-0.5
constexpr float EPSK  = 1e-4f;
constexpr float EPSD  = 1e-6f;
constexpr float QSC   = 0.125f;                 // 64^-0.5

__device__ __forceinline__ unsigned enc_f(float f) {
    unsigned u = __float_as_uint(f);
    return (u & 0x80000000u) ? ~u : (u | 0x80000000u);
}
__device__ __forceinline__ float dec_f(unsigned u) {
    unsigned b = (u & 0x80000000u) ? (u ^ 0x80000000u) : ~u;
    return __uint_as_float(b);
}

// Compute one head's projection for 128 time rows into LDS.
// out[r][o] = (sum_d src[t0+r, b, d] * W[h*64+o, d] + bias[h*64+o]) * scale
// xs: LDS [128][65] staging, wl: LDS [64][65], outp stride = ost.
__device__ void proj_head128(const float* __restrict__ src, const float* __restrict__ W,
                             const float* __restrict__ bias, int t0, int b, int h,
                             float scale, float* xs, float* wl, float* outp, int ost, int tid)
{
    for (int i = tid; i < 128*64; i += NTHR) {
        int r = i >> 6, d = i & 63;
        xs[r*65 + d] = src[((size_t)(t0 + r)*BSZ + b)*HD + d];
    }
    for (int i = tid; i < 64*64; i += NTHR) {
        int o = i >> 6, d = i & 63;
        wl[o*65 + d] = W[(h*HD + o)*HD + d];
    }
    __syncthreads();
    const int rb = tid >> 3, ob = tid & 7;  // 32 row-blocks x 8 col-blocks
    float acc[4][8];
    #pragma unroll
    for (int i = 0; i < 4; ++i)
        #pragma unroll
        for (int j = 0; j < 8; ++j) acc[i][j] = 0.f;
    for (int d = 0; d < 64; ++d) {
        float xv[4], wv[8];
        #pragma unroll
        for (int i = 0; i < 4; ++i) xv[i] = xs[(rb*4 + i)*65 + d];
        #pragma unroll
        for (int j = 0; j < 8; ++j) wv[j] = wl[(ob*8 + j)*65 + d];
        #pragma unroll
        for (int i = 0; i < 4; ++i)
            #pragma unroll
            for (int j = 0; j < 8; ++j) acc[i][j] = fmaf(xv[i], wv[j], acc[i][j]);
    }
    #pragma unroll
    for (int i = 0; i < 4; ++i)
        #pragma unroll
        for (int j = 0; j < 8; ++j) {
            int r = rb*4 + i, o = ob*8 + j;
            outp[r*ost + o] = (acc[i][j] + bias[h*HD + o]) * scale;
        }
    __syncthreads();
}

// diag[t] = 0.5 * sum_d hsrc[t][d]^2   (hsrc stride 68)
__device__ void calc_diag(const float* hsrc, float* diag, int tid)
{
    int t = tid >> 1, half = tid & 1;
    float s = 0.f;
    for (int d = half*32; d < half*32 + 32; ++d) { float v = hsrc[t*68 + d]; s = fmaf(v, v, s); }
    s += __shfl_xor(s, 1);
    if (!half) diag[t] = 0.5f * s;
    __syncthreads();
}

__global__ void kernInit(unsigned* kmax_u)
{
    if (threadIdx.x == 0 && blockIdx.x == 0) *kmax_u = 0x007FFFFFu;  // enc(-inf)
}

// ---------------- kernP: global max of dd_k ----------------
__launch_bounds__(NTHR, 1)
__global__ void kernP(const float* __restrict__ kin, const float* __restrict__ Wk,
                      const float* __restrict__ bk, const float* __restrict__ proj,
                      unsigned* __restrict__ kmax_u)
{
    extern __shared__ float sm[];
    float* kh = sm;             // [128][68] = 8704
    float* xs = sm + 8704;      // 8320
    float* wl = sm + 17024;     // 4160 -> ends 21184
    float* pj = sm + 8704;      // alias xs: [38][68] = 2584
    float* red = sm + 21184;    // 4
    const int tid = threadIdx.x;
    const int bh = blockIdx.x, seg = blockIdx.y;
    const int b = bh >> 3, h = bh & 7, t0 = seg*SC;

    proj_head128(kin, Wk, bk, t0, b, h, DN, xs, wl, kh, 68, tid);

    const int t = tid >> 1, mh = tid & 1;
    float mx = -3.0e38f;
    for (int c = 0; c < 7; ++c) {
        __syncthreads();
        for (int i = tid; i < 38*64; i += NTHR) {
            int mi = i >> 6, d = i & 63;
            pj[mi*68 + d] = proj[(c*38 + mi)*HD + d];
        }
        __syncthreads();
        float facc[19];
        #pragma unroll
        for (int mi = 0; mi < 19; ++mi) facc[mi] = 0.f;
        for (int d4 = 0; d4 < 16; ++d4) {
            const float4 qv = *(const float4*)&kh[t*68 + d4*4];
            #pragma unroll
            for (int mi = 0; mi < 19; ++mi) {
                const float4 pv = *(const float4*)&pj[(mh*19 + mi)*68 + d4*4];
                float f = facc[mi];
                f = fmaf(qv.x, pv.x, f); f = fmaf(qv.y, pv.y, f);
                f = fmaf(qv.z, pv.z, f); f = fmaf(qv.w, pv.w, f);
                facc[mi] = f;
            }
        }
        #pragma unroll
        for (int mi = 0; mi < 19; ++mi) mx = fmaxf(mx, facc[mi]);
    }
    #pragma unroll
    for (int off = 1; off < 64; off <<= 1) mx = fmaxf(mx, __shfl_xor(mx, off));
    __syncthreads();
    if ((tid & 63) == 0) red[tid >> 6] = mx;
    __syncthreads();
    if (tid == 0) {
        float m4 = fmaxf(fmaxf(red[0], red[1]), fmaxf(red[2], red[3]));
        atomicMax(kmax_u, enc_f(m4));
    }
}

// ---------------- kernA: per-segment S_seg = kf^T v, z_seg ----------------
__launch_bounds__(NTHR, 1)
__global__ void kernA(const float* __restrict__ kin, const float* __restrict__ vin,
                      const float* __restrict__ Wk, const float* __restrict__ bk,
                      const float* __restrict__ Wv, const float* __restrict__ bv,
                      const float* __restrict__ proj, const unsigned* __restrict__ kmax_u,
                      float* __restrict__ Sseg, float* __restrict__ zseg)
{
    extern __shared__ float sm[];
    float* kh = sm;               // [128][68] 8704
    float* vh = sm + 8704;        // [128][68] 8704 -> 17408
    float* pj = sm + 17408;       // [32][68] 2176 -> 19584
    float* kf = sm + 19584;       // [128][40] 5120 -> 24704
    float* diag_k = sm + 24704;   // 128 -> 24832
    float* xs = sm + 24832;       // 8320
    float* wl = sm + 33152;       // 4160 -> 37312
    const int tid = threadIdx.x;
    const int bh = blockIdx.x, seg = blockIdx.y;
    const int b = bh >> 3, h = bh & 7, t0 = seg*SC;

    proj_head128(kin, Wk, bk, t0, b, h, DN,   xs, wl, kh, 68, tid);
    proj_head128(vin, Wv, bv, t0, b, h, 1.0f, xs, wl, vh, 68, tid);
    calc_diag(kh, diag_k, tid);
    const float kmax = dec_f(*kmax_u);

    const int e = tid & 63, mg = tid >> 6;
    const size_t sb = ((size_t)bh*NSEG + seg)*MF;

    for (int c = 0; c < 9; ++c) {
        const int m0 = c*32;
        const int cnt = (m0 + 32 <= MF) ? 32 : (MF - m0);
        __syncthreads();
        for (int i = tid; i < cnt*64; i += NTHR) {
            int mi = i >> 6, d = i & 63;
            pj[mi*68 + d] = proj[(m0 + mi)*HD + d];
        }
        __syncthreads();
        {   // kf chunk (t = tid>>1 row, half of 32 m each; tail stores guarded)
            const int t = tid >> 1, mh2 = tid & 1;
            const float dk = diag_k[t];
            float facc[16];
            #pragma unroll
            for (int mi = 0; mi < 16; ++mi) facc[mi] = 0.f;
            for (int d4 = 0; d4 < 16; ++d4) {
                const float4 kv = *(const float4*)&kh[t*68 + d4*4];
                #pragma unroll
                for (int mi = 0; mi < 16; ++mi) {
                    const float4 pv = *(const float4*)&pj[(mh2*16 + mi)*68 + d4*4];
                    float f = facc[mi];
                    f = fmaf(kv.x, pv.x, f); f = fmaf(kv.y, pv.y, f);
                    f = fmaf(kv.z, pv.z, f); f = fmaf(kv.w, pv.w, f);
                    facc[mi] = f;
                }
            }
            #pragma unroll
            for (int mi = 0; mi < 16; ++mi) {
                int m = mh2*16 + mi;
                if (m < cnt) kf[t*40 + m] = RATIO*(__expf(facc[mi] - dk - kmax) + EPSK);
            }
        }
        __syncthreads();
        float S[8];
        #pragma unroll
        for (int i = 0; i < 8; ++i) S[i] = 0.f;
        for (int s = 0; s < SC; ++s) {
            const float4 k0 = *(const float4*)&kf[s*40 + mg*8];
            const float4 k1 = *(const float4*)&kf[s*40 + mg*8 + 4];
            const float vv = vh[s*68 + e];
            S[0] = fmaf(k0.x, vv, S[0]); S[1] = fmaf(k0.y, vv, S[1]);
            S[2] = fmaf(k0.z, vv, S[2]); S[3] = fmaf(k0.w, vv, S[3]);
            S[4] = fmaf(k1.x, vv, S[4]); S[5] = fmaf(k1.y, vv, S[5]);
            S[6] = fmaf(k1.z, vv, S[6]); S[7] = fmaf(k1.w, vv, S[7]);
        }
        #pragma unroll
        for (int i = 0; i < 8; ++i) {
            int m = mg*8 + i;
            if (m < cnt) Sseg[(sb + m0 + m)*HD + e] = S[i];
        }
        if (tid < cnt) {
            float z = 0.f;
            for (int s = 0; s < SC; ++s) z += kf[s*40 + tid];
            zseg[sb + m0 + tid] = z;
        }
    }
}

// ---------------- kernB: in-place exclusive prefix over segments ----------------
__launch_bounds__(NTHR)
__global__ void kernB(float* __restrict__ Sseg, float* __restrict__ zseg)
{
    extern __shared__ float sm[];
    float* acc  = sm;           // [266*16]
    float* zacc = sm + MF*16;   // [266]
    const int tid = threadIdx.x;
    const int bh = blockIdx.x, eq = blockIdx.y;
    for (int i = tid; i < MF*16; i += NTHR) acc[i] = 0.f;
    if (eq == 0) for (int i = tid; i < MF; i += NTHR) zacc[i] = 0.f;
    // each LDS slot is touched only by its own thread -> no barriers needed
    for (int s = 0; s < NSEG; ++s) {
        const size_t base = ((size_t)bh*NSEG + s)*MF;
        for (int i = tid; i < MF*16; i += NTHR) {
            int m = i >> 4, e2 = (i & 15) + eq*16;
            size_t gi = (base + m)*HD + e2;
            float tv = Sseg[gi];
            Sseg[gi] = acc[i];
            acc[i] += tv;
        }
        if (eq == 0) for (int i = tid; i < MF; i += NTHR) {
            float tv = zseg[base + i];
            zseg[base + i] = zacc[i];
            zacc[i] += tv;
        }
    }
}

// ---------------- kernC: main attention ----------------
__launch_bounds__(NTHR, 1)
__global__ void kernC(const float* __restrict__ qin, const float* __restrict__ kin,
                      const float* __restrict__ vin,
                      const float* __restrict__ Wq, const float* __restrict__ bq,
                      const float* __restrict__ Wk, const float* __restrict__ bk,
                      const float* __restrict__ Wv, const float* __restrict__ bv,
                      const float* __restrict__ proj,
                      const float* __restrict__ Spre, const float* __restrict__ zpre,
                      const unsigned* __restrict__ kmax_u,
                      float* __restrict__ merged)
{
    extern __shared__ float sm[];
    float* qh = sm;               // [128][68] 8704
    float* kh = sm + 8704;        // [128][68] 8704 -> 17408
    float* pj = sm + 17408;       // [38][68] 2584 -> 19992
    float* sp = sm + 19992;       // [38][68] 2584 -> 22576
    float* qf = sm + 22576;       // [128][41] 5248 -> 27824
    float* kT = sm + 27824;       // [38][128] 4864 (slot 5120) -> 32944
    float* diag_q = sm + 32944;   // 128
    float* diag_k = sm + 33072;   // 128
    float* qmax   = sm + 33200;   // 128
    float* denL   = sm + 33328;   // 128
    float* zp     = sm + 33456;   // 38 -> ends 33494
    float* xs   = pj;             // staging alias (17408..25728)
    float* wl   = sm + 25728;     // 4160 (25728..29888, over dead qf/kT)
    float* Amat = kh;             // [128][129] = 16512 (8704..25216)
    float* vh   = qh;             // [128][68] reuse

    const int tid = threadIdx.x;
    const int bh = blockIdx.x, seg = blockIdx.y;
    const int b = bh >> 3, h = bh & 7;
    const int t0 = seg * SC;
    const float kmax = dec_f(*kmax_u);

    proj_head128(qin, Wq, bq, t0, b, h, QSC*DN, xs, wl, qh, 68, tid);
    proj_head128(kin, Wk, bk, t0, b, h, DN,     xs, wl, kh, 68, tid);
    calc_diag(qh, diag_q, tid);
    calc_diag(kh, diag_k, tid);

    const int tf = tid >> 1, mhalf = tid & 1;

    // pass 1: per-row max of dd_q over all 266 features
    {
        float mx = -3.0e38f;
        for (int c = 0; c < 7; ++c) {
            __syncthreads();
            for (int i = tid; i < 38*64; i += NTHR) {
                int mi = i >> 6, d = i & 63;
                pj[mi*68 + d] = proj[(c*38 + mi)*HD + d];
            }
            __syncthreads();
            float facc[19];
            #pragma unroll
            for (int mi = 0; mi < 19; ++mi) facc[mi] = 0.f;
            for (int d4 = 0; d4 < 16; ++d4) {
                const float4 qv = *(const float4*)&qh[tf*68 + d4*4];
                #pragma unroll
                for (int mi = 0; mi < 19; ++mi) {
                    const float4 pv = *(const float4*)&pj[(mhalf*19 + mi)*68 + d4*4];
                    float f = facc[mi];
                    f = fmaf(qv.x, pv.x, f); f = fmaf(qv.y, pv.y, f);
                    f = fmaf(qv.z, pv.z, f); f = fmaf(qv.w, pv.w, f);
                    facc[mi] = f;
                }
            }
            #pragma unroll
            for (int mi = 0; mi < 19; ++mi) mx = fmaxf(mx, facc[mi]);
        }
        mx = fmaxf(mx, __shfl_xor(mx, 1));
        if (!mhalf) qmax[tf] = mx;
        __syncthreads();
    }

    const int i4 = tid >> 4;    // 8 t-rows: i4*8..+7
    const int j4 = tid & 15;    // 8 s-cols: j4*8..+7 ; 4 e-cols: j4*4..+3
    float a[8][8], nu[8][4];
    #pragma unroll
    for (int r = 0; r < 8; ++r) {
        #pragma unroll
        for (int c = 0; c < 8; ++c) a[r][c] = 0.f;
        #pragma unroll
        for (int e = 0; e < 4; ++e) nu[r][e] = 0.f;
    }
    float pden = 0.f, psum = 0.f;
    const size_t sbase = ((size_t)bh*NSEG + seg)*MF;

    // pass 2: features + A accumulation + inter-segment num/den
    for (int c = 0; c < 7; ++c) {
        __syncthreads();
        for (int i = tid; i < 38*64; i += NTHR) {
            int mi = i >> 6, d = i & 63;
            pj[mi*68 + d] = proj[(c*38 + mi)*HD + d];
            sp[mi*68 + d] = Spre[(sbase + c*38 + mi)*HD + d];
        }
        if (tid < 38) zp[tid] = zpre[sbase + c*38 + tid];
        __syncthreads();
        {   // qf chunk
            const float dq = diag_q[tf], qm = qmax[tf];
            float facc[19];
            #pragma unroll
            for (int mi = 0; mi < 19; ++mi) facc[mi] = 0.f;
            for (int d4 = 0; d4 < 16; ++d4) {
                const float4 qv = *(const float4*)&qh[tf*68 + d4*4];
                #pragma unroll
                for (int mi = 0; mi < 19; ++mi) {
                    const float4 pv = *(const float4*)&pj[(mhalf*19 + mi)*68 + d4*4];
                    float f = facc[mi];
                    f = fmaf(qv.x, pv.x, f); f = fmaf(qv.y, pv.y, f);
                    f = fmaf(qv.z, pv.z, f); f = fmaf(qv.w, pv.w, f);
                    facc[mi] = f;
                }
            }
            #pragma unroll
            for (int mi = 0; mi < 19; ++mi) {
                int m = mhalf*19 + mi;
                float f = RATIO*(__expf(facc[mi] - dq - qm) + EPSK);
                qf[tf*41 + m] = f;
                pden = fmaf(f, zp[m], pden);
                psum += f;
            }
        }
        {   // kf chunk (transposed store)
            const float dk = diag_k[tf];
            float facc[19];
            #pragma unroll
            for (int mi = 0; mi < 19; ++mi) facc[mi] = 0.f;
            for (int d4 = 0; d4 < 16; ++d4) {
                const float4 kv = *(const float4*)&kh[tf*68 + d4*4];
                #pragma unroll
                for (int mi = 0; mi < 19; ++mi) {
                    const float4 pv = *(const float4*)&pj[(mhalf*19 + mi)*68 + d4*4];
                    float f = facc[mi];
                    f = fmaf(kv.x, pv.x, f); f = fmaf(kv.y, pv.y, f);
                    f = fmaf(kv.z, pv.z, f); f = fmaf(kv.w, pv.w, f);
                    facc[mi] = f;
                }
            }
            #pragma unroll
            for (int mi = 0; mi < 19; ++mi) {
                int m = mhalf*19 + mi;
                kT[m*128 + tf] = RATIO*(__expf(facc[mi] - dk - kmax) + EPSK);
            }
        }
        __syncthreads();
        for (int m = 0; m < 38; ++m) {
            float qv[8];
            #pragma unroll
            for (int r = 0; r < 8; ++r) qv[r] = qf[(i4*8 + r)*41 + m];
            const float4 k0 = *(const float4*)&kT[m*128 + j4*8];
            const float4 k1 = *(const float4*)&kT[m*128 + j4*8 + 4];
            const float4 sv = *(const float4*)&sp[m*68 + j4*4];
            #pragma unroll
            for (int r = 0; r < 8; ++r) {
                a[r][0] = fmaf(qv[r], k0.x, a[r][0]); a[r][1] = fmaf(qv[r], k0.y, a[r][1]);
                a[r][2] = fmaf(qv[r], k0.z, a[r][2]); a[r][3] = fmaf(qv[r], k0.w, a[r][3]);
                a[r][4] = fmaf(qv[r], k1.x, a[r][4]); a[r][5] = fmaf(qv[r], k1.y, a[r][5]);
                a[r][6] = fmaf(qv[r], k1.z, a[r][6]); a[r][7] = fmaf(qv[r], k1.w, a[r][7]);
                nu[r][0] = fmaf(qv[r], sv.x, nu[r][0]); nu[r][1] = fmaf(qv[r], sv.y, nu[r][1]);
                nu[r][2] = fmaf(qv[r], sv.z, nu[r][2]); nu[r][3] = fmaf(qv[r], sv.w, nu[r][3]);
            }
        }
    }

    {   // den base: qf . z_pre + EPSD * sum(qf)
        float pd = fmaf(EPSD, psum, pden);
        pd += __shfl_xor(pd, 1);
        if (!mhalf) denL[tf] = pd;
        __syncthreads();
    }

    // v head (into qh slot; staging over dead pj/sp/qf)
    proj_head128(vin, Wv, bv, t0, b, h, 1.0f, xs, wl, vh, 68, tid);

    {   // mask A (strict causal), rowsum -> den, store A to LDS
        float rs[8];
        #pragma unroll
        for (int r = 0; r < 8; ++r) rs[r] = 0.f;
        #pragma unroll
        for (int r = 0; r < 8; ++r) {
            const int tr = i4*8 + r;
            #pragma unroll
            for (int c = 0; c < 8; ++c) {
                const int s = j4*8 + c;
                float av = (s < tr) ? a[r][c] : 0.f;
                Amat[tr*129 + s] = av;
                rs[r] += av;
            }
        }
        #pragma unroll
        for (int off = 1; off < 16; off <<= 1) {
            #pragma unroll
            for (int r = 0; r < 8; ++r) rs[r] += __shfl_xor(rs[r], off);
        }
        __syncthreads();
        if (j4 == 0) {
            #pragma unroll
            for (int r = 0; r < 8; ++r) denL[i4*8 + r] += rs[r];
        }
        __syncthreads();
    }

    // num += A @ v
    for (int s = 0; s < SC; ++s) {
        const float4 vv = *(const float4*)&vh[s*68 + j4*4];
        #pragma unroll
        for (int r = 0; r < 8; ++r) {
            const float av = Amat[(i4*8 + r)*129 + s];
            nu[r][0] = fmaf(av, vv.x, nu[r][0]); nu[r][1] = fmaf(av, vv.y, nu[r][1]);
            nu[r][2] = fmaf(av, vv.z, nu[r][2]); nu[r][3] = fmaf(av, vv.w, nu[r][3]);
        }
    }

    #pragma unroll
    for (int r = 0; r < 8; ++r) {
        const int t = t0 + i4*8 + r;
        const float inv = 1.0f / denL[i4*8 + r];
        #pragma unroll
        for (int e = 0; e < 4; ++e)
            merged[((size_t)b*T_LEN + t)*512 + h*64 + j4*4 + e] = nu[r][e] * inv;
    }
}

// ---------------- kernD: output projection + transpose ----------------
__launch_bounds__(NTHR)
__global__ void kernD(const float* __restrict__ merged, const float* __restrict__ Wo,
                      const float* __restrict__ bo, float* __restrict__ out)
{
    extern __shared__ float sm[];
    float* ms = sm;          // [64][65]
    float* wl = sm + 4160;   // [64][65]
    const int tid = threadIdx.x;
    const int r0 = blockIdx.x * 64;
    const int rb = tid >> 4, eb = tid & 15;
    float acc[4][4];
    #pragma unroll
    for (int i = 0; i < 4; ++i)
        #pragma unroll
        for (int j = 0; j < 4; ++j) acc[i][j] = 0.f;
    for (int ko = 0; ko < 8; ++ko) {
        __syncthreads();
        for (int i = tid; i < 64*64; i += NTHR) {
            int r = i >> 6, d = i & 63;
            ms[r*65 + d] = merged[((size_t)(r0 + r))*512 + ko*64 + d];
            wl[r*65 + d] = Wo[r*512 + ko*64 + d];
        }
        __syncthreads();
        for (int d = 0; d < 64; ++d) {
            float xv[4], wv[4];
            #pragma unroll
            for (int i = 0; i < 4; ++i) xv[i] = ms[(rb*4 + i)*65 + d];
            #pragma unroll
            for (int j = 0; j < 4; ++j) wv[j] = wl[(eb*4 + j)*65 + d];
            #pragma unroll
            for (int i = 0; i < 4; ++i)
                #pragma unroll
                for (int j = 0; j < 4; ++j) acc[i][j] = fmaf(xv[i], wv[j], acc[i][j]);
        }
    }
    #pragma unroll
    for (int i = 0; i < 4; ++i) {
        const int row = r0 + rb*4 + i;
        const int bb = row >> 11, t = row & (T_LEN - 1);
        #pragma unroll
        for (int j = 0; j < 4; ++j) {
            const int e = eb*4 + j;
            out[((size_t)t*BSZ + bb)*HD + e] = acc[i][j] + bo[e];
        }
    }
}

extern "C" void kernel_launch(void* const* d_in, const int* in_sizes, int n_in,
                              void* d_out, int out_size, void* d_ws, size_t ws_size,
                              hipStream_t stream)
{
    (void)in_sizes; (void)n_in; (void)out_size; (void)ws_size;
    const float* qin  = (const float*)d_in[0];
    const float* kin  = (const float*)d_in[1];
    const float* vin  = (const float*)d_in[2];
    const float* Wq   = (const float*)d_in[3];
    const float* bq   = (const float*)d_in[4];
    const float* Wk   = (const float*)d_in[5];
    const float* bk   = (const float*)d_in[6];
    const float* Wv   = (const float*)d_in[7];
    const float* bv   = (const float*)d_in[8];
    const float* Wo   = (const float*)d_in[9];
    const float* bo   = (const float*)d_in[10];
    const float* proj = (const float*)d_in[11];

    float* ws = (float*)d_ws;
    unsigned* kmax_u = (unsigned*)ws;
    float* Sseg   = ws + 16;
    float* zseg   = Sseg + (size_t)BH*NSEG*MF*HD;   // 34,865,152 floats
    float* merged = zseg + (size_t)BH*NSEG*MF;      //    544,768 floats
    float* out = (float*)d_out;                     // merged: 16,777,216 -> ~209 MB total

    const int LDS_P = 21188 * 4;
    const int LDS_A = 37312 * 4;
    const int LDS_B = (MF*16 + MF) * 4;
    const int LDS_C = 33494 * 4;
    const int LDS_D = 8320 * 4;
    (void)hipFuncSetAttribute((const void*)kernP, hipFuncAttributeMaxDynamicSharedMemorySize, LDS_P);
    (void)hipFuncSetAttribute((const void*)kernA, hipFuncAttributeMaxDynamicSharedMemorySize, LDS_A);
    (void)hipFuncSetAttribute((const void*)kernC, hipFuncAttributeMaxDynamicSharedMemorySize, LDS_C);

    kernInit<<<1, 64, 0, stream>>>(kmax_u);
    kernP<<<dim3(BH, NSEG), NTHR, LDS_P, stream>>>(kin, Wk, bk, proj, kmax_u);
    kernA<<<dim3(BH, NSEG), NTHR, LDS_A, stream>>>(kin, vin, Wk, bk, Wv, bv, proj, kmax_u, Sseg, zseg);
    kernB<<<dim3(BH, 4),    NTHR, LDS_B, stream>>>(Sseg, zseg);
    kernC<<<dim3(BH, NSEG), NTHR, LDS_C, stream>>>(qin, kin, vin, Wq, bq, Wk, bk, Wv, bv,
                                                   proj, Sseg, zseg, kmax_u, merged);
    kernD<<<512, NTHR, LDS_D, stream>>>(merged, Wo, bo, out);
}

// Round 2
// 386.040 us; speedup vs baseline: 11.9583x; 11.9583x over previous
//
#include <hip/hip_runtime.h>

#define T_LEN 2048
#define BSZ 16
#define NHEAD 8
#define BH 128
#define NSEG 16
#define SC 128
#define MF 266
#define MFP 288
#define CH 96

constexpr float DN    = 0.3535533905932738f;    // 64^-0.25
constexpr float RATIO = 0.06131393394849658f;   // 266^-0.5
constexpr float EPSK  = 1e-4f;
constexpr float EPSD  = 1e-6f;
constexpr float QSC   = 0.125f;                 // 64^-0.5

typedef unsigned short u16;
typedef __attribute__((ext_vector_type(8))) short short8;
typedef __attribute__((ext_vector_type(4))) float f32x4;
typedef __attribute__((ext_vector_type(4))) unsigned short us4;

#define MFMA16(a,b,c) __builtin_amdgcn_mfma_f32_16x16x32_bf16(a,b,c,0,0,0)

__device__ __forceinline__ u16 f2bf(float f){
    unsigned u = __float_as_uint(f);
    return (u16)((u + 0x7FFFu + ((u >> 16) & 1u)) >> 16);
}
__device__ __forceinline__ float bf2f(u16 u){ return __uint_as_float(((unsigned)u) << 16); }
__device__ __forceinline__ unsigned enc_f(float f){
    unsigned u = __float_as_uint(f);
    return (u & 0x80000000u) ? ~u : (u | 0x80000000u);
}
__device__ __forceinline__ float dec_f(unsigned u){
    unsigned b = (u & 0x80000000u) ? (u ^ 0x80000000u) : ~u;
    return __uint_as_float(b);
}

// load rows of proj (f32 [266][64]) into LDS bf16 [nrows][72], zero rows for m>=266
__device__ __forceinline__ void load_proj(const float* __restrict__ proj, u16* pjb,
                                          int m0, int nrows, int tid, int nthr)
{
    for (int i = tid; i < nrows * 8; i += nthr) {
        int mi = i >> 3, d8 = (i & 7) * 8;
        int m = m0 + mi;
        us4 lo = 0, hi = 0;
        if (m < MF) {
            const float* s = proj + (size_t)m * 64 + d8;
            float4 x0 = *(const float4*)s;
            float4 x1 = *(const float4*)(s + 4);
            lo[0]=f2bf(x0.x); lo[1]=f2bf(x0.y); lo[2]=f2bf(x0.z); lo[3]=f2bf(x0.w);
            hi[0]=f2bf(x1.x); hi[1]=f2bf(x1.y); hi[2]=f2bf(x1.z); hi[3]=f2bf(x1.w);
        }
        *(us4*)(pjb + mi * 72 + d8)     = lo;
        *(us4*)(pjb + mi * 72 + d8 + 4) = hi;
    }
}

// copy 128 bf16 head-rows (64 wide) from ws into LDS [128][72]
__device__ __forceinline__ void load_head(const u16* __restrict__ src, u16* dst,
                                          size_t row0, int tid, int nthr)
{
    for (int i = tid; i < 128 * 8; i += nthr) {
        int r = i >> 3, d8 = (i & 7) * 8;
        *(short8*)(dst + r * 72 + d8) = *(const short8*)(src + (row0 + r) * 64 + d8);
    }
}

__global__ void kernInit(unsigned* kmax_u)
{
    if (threadIdx.x == 0 && blockIdx.x == 0) *kmax_u = 0x007FFFFFu;   // enc(-inf)
}

// ---------------- kernH: head projections -> bf16 ws (+ diag for q,k) ----------------
__launch_bounds__(256)
__global__ void kernH(const float* __restrict__ qin, const float* __restrict__ kin,
                      const float* __restrict__ vin,
                      const float* __restrict__ Wq, const float* __restrict__ bq,
                      const float* __restrict__ Wk, const float* __restrict__ bk,
                      const float* __restrict__ Wv, const float* __restrict__ bv,
                      u16* __restrict__ qh, u16* __restrict__ kh, u16* __restrict__ vh,
                      float* __restrict__ dqw, float* __restrict__ dkw)
{
    extern __shared__ char smh[];
    u16*   xb  = (u16*)smh;             // [128][72]  18432 B
    u16*   wb  = (u16*)(smh + 18432);   // [64][72]    9216 B
    float* bsh = (float*)(smh + 27648); // [64]         256 B

    const int tid = threadIdx.x;
    const int iv  = blockIdx.y;
    const int r0  = blockIdx.x * 128;
    const float* src  = (iv == 0) ? qin : (iv == 1) ? kin : vin;
    const float* W    = (iv == 0) ? Wq  : (iv == 1) ? Wk  : Wv;
    const float* bias = (iv == 0) ? bq  : (iv == 1) ? bk  : bv;
    u16*   outp  = (iv == 0) ? qh : (iv == 1) ? kh : vh;
    float* diagp = (iv == 0) ? dqw : (iv == 1) ? dkw : nullptr;
    const float scale = (iv == 0) ? QSC * DN : (iv == 1) ? DN : 1.0f;

    // stage x rows (f32 -> bf16)
    for (int i = tid; i < 128 * 8; i += 256) {
        int r = i >> 3, d8 = (i & 7) * 8;
        const float* s = src + (size_t)(r0 + r) * 64 + d8;
        float4 x0 = *(const float4*)s, x1 = *(const float4*)(s + 4);
        us4 lo, hi;
        lo[0]=f2bf(x0.x); lo[1]=f2bf(x0.y); lo[2]=f2bf(x0.z); lo[3]=f2bf(x0.w);
        hi[0]=f2bf(x1.x); hi[1]=f2bf(x1.y); hi[2]=f2bf(x1.z); hi[3]=f2bf(x1.w);
        *(us4*)(xb + r * 72 + d8)     = lo;
        *(us4*)(xb + r * 72 + d8 + 4) = hi;
    }

    const int c = tid & 15, g = (tid >> 4) & 3, w = tid >> 6;

    for (int h = 0; h < NHEAD; ++h) {
        __syncthreads();
        for (int i = tid; i < 64 * 8; i += 256) {
            int r = i >> 3, d8 = (i & 7) * 8;
            const float* s = W + ((size_t)(h * 64 + r)) * 64 + d8;
            float4 x0 = *(const float4*)s, x1 = *(const float4*)(s + 4);
            us4 lo, hi;
            lo[0]=f2bf(x0.x); lo[1]=f2bf(x0.y); lo[2]=f2bf(x0.z); lo[3]=f2bf(x0.w);
            hi[0]=f2bf(x1.x); hi[1]=f2bf(x1.y); hi[2]=f2bf(x1.z); hi[3]=f2bf(x1.w);
            *(us4*)(wb + r * 72 + d8)     = lo;
            *(us4*)(wb + r * 72 + d8 + 4) = hi;
        }
        if (tid < 64) bsh[tid] = bias[h * 64 + tid];
        __syncthreads();

        for (int mi = 0; mi < 2; ++mi) {
            const int mt = w * 2 + mi;
            short8 a0 = *(const short8*)(xb + (mt * 16 + c) * 72 + g * 8);
            short8 a1 = *(const short8*)(xb + (mt * 16 + c) * 72 + 32 + g * 8);
            float sq[4] = {0.f, 0.f, 0.f, 0.f};
            #pragma unroll
            for (int nt = 0; nt < 4; ++nt) {
                short8 b0 = *(const short8*)(wb + (nt * 16 + c) * 72 + g * 8);
                short8 b1 = *(const short8*)(wb + (nt * 16 + c) * 72 + 32 + g * 8);
                f32x4 acc = 0;
                acc = MFMA16(a0, b0, acc);
                acc = MFMA16(a1, b1, acc);
                const float bv2 = bsh[nt * 16 + c];
                #pragma unroll
                for (int r = 0; r < 4; ++r) {
                    float y = (acc[r] + bv2) * scale;
                    sq[r] = fmaf(y, y, sq[r]);
                    int rr = r0 + mt * 16 + g * 4 + r;
                    int t = rr >> 4, bb = rr & 15;
                    outp[(((size_t)(bb * 8 + h)) * T_LEN + t) * 64 + nt * 16 + c] = f2bf(y);
                }
            }
            if (diagp) {
                #pragma unroll
                for (int r = 0; r < 4; ++r) {
                    #pragma unroll
                    for (int off = 1; off < 16; off <<= 1) sq[r] += __shfl_xor(sq[r], off);
                    if (c == 0) {
                        int rr = r0 + mt * 16 + g * 4 + r;
                        int t = rr >> 4, bb = rr & 15;
                        diagp[((size_t)(bb * 8 + h)) * T_LEN + t] = 0.5f * sq[r];
                    }
                }
            }
        }
    }
}

// ---------------- kernP: global max of dd_k (MFMA) ----------------
__launch_bounds__(256)
__global__ void kernP(const u16* __restrict__ kh, const float* __restrict__ proj,
                      unsigned* __restrict__ kmax_u)
{
    extern __shared__ char smp[];
    u16* khb = (u16*)smp;            // [128][72] 18432
    u16* pjb = (u16*)(smp + 18432);  // [96][72]  13824
    __shared__ float red[4];

    const int tid = threadIdx.x;
    const int bh = blockIdx.x, seg = blockIdx.y, t0 = seg * SC;
    const int c = tid & 15, g = (tid >> 4) & 3, w = tid >> 6;

    load_head(kh, khb, (size_t)bh * T_LEN + t0, tid, 256);
    __syncthreads();

    short8 a0[2], a1[2];
    #pragma unroll
    for (int mi = 0; mi < 2; ++mi) {
        const int row = (w * 2 + mi) * 16 + c;
        a0[mi] = *(const short8*)(khb + row * 72 + g * 8);
        a1[mi] = *(const short8*)(khb + row * 72 + 32 + g * 8);
    }

    float mx = -3.0e38f;
    for (int ch = 0; ch < 3; ++ch) {
        __syncthreads();
        load_proj(proj, pjb, ch * CH, CH, tid, 256);
        __syncthreads();
        #pragma unroll
        for (int mi = 0; mi < 2; ++mi) {
            #pragma unroll
            for (int nt = 0; nt < 6; ++nt) {
                short8 b0 = *(const short8*)(pjb + (nt * 16 + c) * 72 + g * 8);
                short8 b1 = *(const short8*)(pjb + (nt * 16 + c) * 72 + 32 + g * 8);
                f32x4 dd = 0;
                dd = MFMA16(a0[mi], b0, dd);
                dd = MFMA16(a1[mi], b1, dd);
                mx = fmaxf(mx, fmaxf(fmaxf(dd[0], dd[1]), fmaxf(dd[2], dd[3])));
            }
        }
    }
    #pragma unroll
    for (int off = 1; off < 64; off <<= 1) mx = fmaxf(mx, __shfl_xor(mx, off));
    __syncthreads();
    if ((tid & 63) == 0) red[w] = mx;
    __syncthreads();
    if (tid == 0) {
        float m4 = fmaxf(fmaxf(red[0], red[1]), fmaxf(red[2], red[3]));
        atomicMax(kmax_u, enc_f(m4));
    }
}

// ---------------- kernA: S_seg = kf^T [v | 1]  (col 64 = z_seg) ----------------
__launch_bounds__(512)
__global__ void kernA(const u16* __restrict__ kh, const u16* __restrict__ vh,
                      const float* __restrict__ diagk, const float* __restrict__ proj,
                      const unsigned* __restrict__ kmax_u,
                      u16* __restrict__ Sseg, u16* __restrict__ zseg)
{
    extern __shared__ char sma[];
    u16* khb = (u16*)sma;            // [128][72] 18432
    u16* vTb = (u16*)(sma + 18432);  // [80][136] 21760
    u16* pjb = (u16*)(sma + 40192);  // [96][72]  13824
    u16* kfT = (u16*)(sma + 54016);  // [96][136] 26112   -> total 80128

    const int tid = threadIdx.x;
    const int bh = blockIdx.x, seg = blockIdx.y, t0 = seg * SC;
    const int c = tid & 15, g = (tid >> 4) & 3, w = tid >> 6;
    const size_t sb = ((size_t)bh * NSEG + seg) * MF;
    const float kmax = dec_f(*kmax_u);

    load_head(kh, khb, (size_t)bh * T_LEN + t0, tid, 512);
    // vT transpose: vT[e][s] = vh[t0+s][e]; row 64 = ones; rows 65..79 = 0
    for (int i = tid; i < 128 * 64; i += 512) {
        int s = i >> 6, e = i & 63;
        vTb[e * 136 + s] = vh[((size_t)bh * T_LEN + t0 + s) * 64 + e];
    }
    if (tid < 128) vTb[64 * 136 + tid] = 0x3F80;   // bf16(1.0)
    for (int i = tid; i < 15 * 128; i += 512) {
        int r = i >> 7, s = i & 127;
        vTb[(65 + r) * 136 + s] = 0;
    }
    __syncthreads();

    short8 ak0 = *(const short8*)(khb + (w * 16 + c) * 72 + g * 8);
    short8 ak1 = *(const short8*)(khb + (w * 16 + c) * 72 + 32 + g * 8);
    float dk[4];
    #pragma unroll
    for (int r = 0; r < 4; ++r)
        dk[r] = diagk[(size_t)bh * T_LEN + t0 + w * 16 + g * 4 + r];

    for (int ch = 0; ch < 3; ++ch) {
        const int mbase = ch * CH;
        __syncthreads();
        load_proj(proj, pjb, mbase, CH, tid, 512);
        __syncthreads();
        // kf features -> kfT (transposed)
        #pragma unroll
        for (int nt = 0; nt < 6; ++nt) {
            short8 b0 = *(const short8*)(pjb + (nt * 16 + c) * 72 + g * 8);
            short8 b1 = *(const short8*)(pjb + (nt * 16 + c) * 72 + 32 + g * 8);
            f32x4 dd = 0;
            dd = MFMA16(ak0, b0, dd);
            dd = MFMA16(ak1, b1, dd);
            const int m = mbase + nt * 16 + c;
            us4 kw;
            #pragma unroll
            for (int r = 0; r < 4; ++r) {
                float kv = (m < MF) ? RATIO * (__expf(dd[r] - dk[r] - kmax) + EPSK) : 0.f;
                kw[r] = f2bf(kv);
            }
            *(us4*)(kfT + (nt * 16 + c) * 136 + w * 16 + g * 4) = kw;
        }
        __syncthreads();
        // S chunk: D[m][e] = sum_s kfT[m][s] * vT[e][s]
        for (int tt = w; tt < 30; tt += 8) {
            const int mt = tt / 5, nt = tt % 5;
            f32x4 acc = 0;
            #pragma unroll
            for (int ks = 0; ks < 4; ++ks) {
                short8 a = *(const short8*)(kfT + (mt * 16 + c) * 136 + ks * 32 + g * 8);
                short8 b = *(const short8*)(vTb + (nt * 16 + c) * 136 + ks * 32 + g * 8);
                acc = MFMA16(a, b, acc);
            }
            #pragma unroll
            for (int r = 0; r < 4; ++r) {
                int m = mbase + mt * 16 + g * 4 + r;
                if (m < MF) {
                    if (nt < 4) Sseg[(sb + m) * 64 + nt * 16 + c] = f2bf(acc[r]);
                    else if (c == 0) zseg[sb + m] = f2bf(acc[r]);
                }
            }
        }
    }
}

// ---------------- kernB: exclusive prefix over segments (bf16 in/out) ----------------
__launch_bounds__(256)
__global__ void kernB(u16* __restrict__ Sseg, u16* __restrict__ zseg)
{
    extern __shared__ float smb[];
    float* acc  = smb;            // [266*16]
    float* zacc = smb + MF * 16;  // [266]
    const int tid = threadIdx.x;
    const int bh = blockIdx.x, eq = blockIdx.y;
    for (int i = tid; i < MF * 16; i += 256) acc[i] = 0.f;
    if (eq == 0) for (int i = tid; i < MF; i += 256) zacc[i] = 0.f;
    for (int s = 0; s < NSEG; ++s) {
        const size_t base = ((size_t)bh * NSEG + s) * MF;
        for (int i = tid; i < MF * 16; i += 256) {
            int m = i >> 4, e2 = (i & 15) + eq * 16;
            size_t gi = (base + m) * 64 + e2;
            float tv = bf2f(Sseg[gi]);
            Sseg[gi] = f2bf(acc[i]);
            acc[i] += tv;
        }
        if (eq == 0) for (int i = tid; i < MF; i += 256) {
            float tv = bf2f(zseg[base + i]);
            zseg[base + i] = f2bf(zacc[i]);
            zacc[i] += tv;
        }
    }
}

// ---------------- kernC: main attention (all MFMA) ----------------
__launch_bounds__(512)
__global__ void kernC(const u16* __restrict__ qh, const u16* __restrict__ kh,
                      const u16* __restrict__ vh,
                      const float* __restrict__ diagq, const float* __restrict__ diagk,
                      const float* __restrict__ proj,
                      const u16* __restrict__ Spre, const u16* __restrict__ zpre,
                      const unsigned* __restrict__ kmax_u,
                      u16* __restrict__ merged)
{
    extern __shared__ char smc[];
    u16* pjf = (u16*)smc;             // [288][72] 41472 (full proj, resident)
    u16* qhb = (u16*)(smc + 41472);   // [128][72] 18432
    u16* khb = (u16*)(smc + 59904);   // [128][72] 18432
    u16* qfb = (u16*)(smc + 78336);   // [128][104] bf16 26624
    u16* kfb = (u16*)(smc + 104960);  // [128][104] 26624
    u16* STb = (u16*)(smc + 131584);  // [80][104]  16640  -> 148224 total
    u16* Ab  = (u16*)smc;             // alias pjf: [128][136] 34816
    u16* vTb = (u16*)(smc + 41472);   // alias qhb/khb: [64][136] 17408

    const int tid = threadIdx.x;
    const int bh = blockIdx.x, seg = blockIdx.y;
    const int bb = bh >> 3, hh = bh & 7;
    const int t0 = seg * SC;
    const int c = tid & 15, g = (tid >> 4) & 3, w = tid >> 6;
    const size_t sbase = ((size_t)bh * NSEG + seg) * MF;
    const float kmax = dec_f(*kmax_u);

    load_head(qh, qhb, (size_t)bh * T_LEN + t0, tid, 512);
    load_head(kh, khb, (size_t)bh * T_LEN + t0, tid, 512);
    load_proj(proj, pjf, 0, MFP, tid, 512);
    __syncthreads();

    short8 aq0 = *(const short8*)(qhb + (w * 16 + c) * 72 + g * 8);
    short8 aq1 = *(const short8*)(qhb + (w * 16 + c) * 72 + 32 + g * 8);
    short8 ak0 = *(const short8*)(khb + (w * 16 + c) * 72 + g * 8);
    short8 ak1 = *(const short8*)(khb + (w * 16 + c) * 72 + 32 + g * 8);
    float dq[4], dk[4];
    #pragma unroll
    for (int r = 0; r < 4; ++r) {
        const size_t t = (size_t)bh * T_LEN + t0 + w * 16 + g * 4 + r;
        dq[r] = diagq[t];
        dk[r] = diagk[t];
    }

    // pass 1: per-row max of dd_q over all features
    float qm[4] = {-3.0e38f, -3.0e38f, -3.0e38f, -3.0e38f};
    for (int nt = 0; nt < 18; ++nt) {
        short8 b0 = *(const short8*)(pjf + (nt * 16 + c) * 72 + g * 8);
        short8 b1 = *(const short8*)(pjf + (nt * 16 + c) * 72 + 32 + g * 8);
        f32x4 dd = 0;
        dd = MFMA16(aq0, b0, dd);
        dd = MFMA16(aq1, b1, dd);
        #pragma unroll
        for (int r = 0; r < 4; ++r) qm[r] = fmaxf(qm[r], dd[r]);
    }
    #pragma unroll
    for (int r = 0; r < 4; ++r)
        #pragma unroll
        for (int off = 1; off < 16; off <<= 1) qm[r] = fmaxf(qm[r], __shfl_xor(qm[r], off));

    // pass 2: features + A accumulation + inter-segment num/den
    f32x4 Aacc[8], nacc[5];
    #pragma unroll
    for (int nt = 0; nt < 8; ++nt) Aacc[nt] = 0;
    #pragma unroll
    for (int nt = 0; nt < 5; ++nt) nacc[nt] = 0;

    for (int ch = 0; ch < 3; ++ch) {
        const int mbase = ch * CH;
        __syncthreads();
        // ST[e][mi]: e<64 = Spre; row 64 = zpre+EPSD; rows 65..79 = 0
        for (int i = tid; i < CH * 16; i += 512) {
            int mi = i >> 4, e4 = (i & 15) * 4;
            int m = mbase + mi;
            u16 w0 = 0, w1 = 0, w2 = 0, w3 = 0;
            if (m < MF) {
                const u16* sp = Spre + (sbase + m) * 64 + e4;
                w0 = sp[0]; w1 = sp[1]; w2 = sp[2]; w3 = sp[3];
            }
            STb[(e4 + 0) * 104 + mi] = w0;
            STb[(e4 + 1) * 104 + mi] = w1;
            STb[(e4 + 2) * 104 + mi] = w2;
            STb[(e4 + 3) * 104 + mi] = w3;
        }
        for (int i = tid; i < CH; i += 512) {
            int m = mbase + i;
            float z = (m < MF) ? bf2f(zpre[sbase + m]) + EPSD : 0.f;
            STb[64 * 104 + i] = f2bf(z);
        }
        for (int i = tid; i < 15 * CH; i += 512)
            STb[(65 + i / CH) * 104 + (i % CH)] = 0;
        // features
        #pragma unroll
        for (int nt = 0; nt < 6; ++nt) {
            const int m = mbase + nt * 16 + c;
            short8 b0 = *(const short8*)(pjf + m * 72 + g * 8);
            short8 b1 = *(const short8*)(pjf + m * 72 + 32 + g * 8);
            f32x4 ddq = 0, ddk = 0;
            ddq = MFMA16(aq0, b0, ddq);
            ddq = MFMA16(aq1, b1, ddq);
            ddk = MFMA16(ak0, b0, ddk);
            ddk = MFMA16(ak1, b1, ddk);
            #pragma unroll
            for (int r = 0; r < 4; ++r) {
                float qv = RATIO * (__expf(ddq[r] - dq[r] - qm[r]) + EPSK);
                float kv = RATIO * (__expf(ddk[r] - dk[r] - kmax) + EPSK);
                if (m >= MF) { qv = 0.f; kv = 0.f; }
                const int row = w * 16 + g * 4 + r;
                qfb[row * 104 + nt * 16 + c] = f2bf(qv);
                kfb[row * 104 + nt * 16 + c] = f2bf(kv);
            }
        }
        __syncthreads();
        short8 af[3];
        #pragma unroll
        for (int ks = 0; ks < 3; ++ks)
            af[ks] = *(const short8*)(qfb + (w * 16 + c) * 104 + ks * 32 + g * 8);
        #pragma unroll
        for (int nt = 0; nt < 8; ++nt) {
            #pragma unroll
            for (int ks = 0; ks < 3; ++ks) {
                short8 b = *(const short8*)(kfb + (nt * 16 + c) * 104 + ks * 32 + g * 8);
                Aacc[nt] = MFMA16(af[ks], b, Aacc[nt]);
            }
        }
        #pragma unroll
        for (int nt = 0; nt < 5; ++nt) {
            #pragma unroll
            for (int ks = 0; ks < 3; ++ks) {
                short8 b = *(const short8*)(STb + (nt * 16 + c) * 104 + ks * 32 + g * 8);
                nacc[nt] = MFMA16(af[ks], b, nacc[nt]);
            }
        }
    }

    // den = (qf.(zpre+EPSD)) broadcast + rowsum(masked A)
    float den[4];
    #pragma unroll
    for (int r = 0; r < 4; ++r) den[r] = __shfl(nacc[4][r], tid & 48);
    float rs[4] = {0.f, 0.f, 0.f, 0.f};
    #pragma unroll
    for (int nt = 0; nt < 8; ++nt) {
        #pragma unroll
        for (int r = 0; r < 4; ++r) {
            const int row = w * 16 + g * 4 + r;
            const int sc2 = nt * 16 + c;
            float av = (sc2 < row) ? Aacc[nt][r] : 0.f;
            Aacc[nt][r] = av;
            rs[r] += av;
        }
    }
    #pragma unroll
    for (int r = 0; r < 4; ++r) {
        #pragma unroll
        for (int off = 1; off < 16; off <<= 1) rs[r] += __shfl_xor(rs[r], off);
        den[r] += rs[r];
    }

    __syncthreads();  // all pass-2 LDS reads done; repurpose proj/qh/kh regions
    // masked A -> bf16 LDS; v^T load
    #pragma unroll
    for (int nt = 0; nt < 8; ++nt)
        #pragma unroll
        for (int r = 0; r < 4; ++r)
            Ab[(w * 16 + g * 4 + r) * 136 + nt * 16 + c] = f2bf(Aacc[nt][r]);
    for (int i = tid; i < 128 * 64; i += 512) {
        int s = i >> 6, e = i & 63;
        vTb[e * 136 + s] = vh[((size_t)bh * T_LEN + t0 + s) * 64 + e];
    }
    __syncthreads();

    // num += A_masked @ v
    short8 af2[4];
    #pragma unroll
    for (int ks = 0; ks < 4; ++ks)
        af2[ks] = *(const short8*)(Ab + (w * 16 + c) * 136 + ks * 32 + g * 8);
    #pragma unroll
    for (int nt = 0; nt < 4; ++nt) {
        #pragma unroll
        for (int ks = 0; ks < 4; ++ks) {
            short8 b = *(const short8*)(vTb + (nt * 16 + c) * 136 + ks * 32 + g * 8);
            nacc[nt] = MFMA16(af2[ks], b, nacc[nt]);
        }
    }

    float rden[4];
    #pragma unroll
    for (int r = 0; r < 4; ++r) rden[r] = 1.0f / den[r];
    #pragma unroll
    for (int nt = 0; nt < 4; ++nt) {
        #pragma unroll
        for (int r = 0; r < 4; ++r) {
            const int t = t0 + w * 16 + g * 4 + r;
            merged[((size_t)bb * T_LEN + t) * 512 + hh * 64 + nt * 16 + c] =
                f2bf(nacc[nt][r] * rden[r]);
        }
    }
}

// ---------------- kernD: output projection + transpose ----------------
__launch_bounds__(256)
__global__ void kernD(const u16* __restrict__ merged, const float* __restrict__ Wo,
                      const float* __restrict__ bo, float* __restrict__ out)
{
    extern __shared__ char smd[];
    u16* mb  = (u16*)smd;            // [128][136] 34816
    u16* wob = (u16*)(smd + 34816);  // [64][136]  17408

    const int tid = threadIdx.x;
    const int r0 = blockIdx.x * 128;
    const int c = tid & 15, g = (tid >> 4) & 3, w = tid >> 6;

    f32x4 acc[2][4];
    #pragma unroll
    for (int mi = 0; mi < 2; ++mi)
        #pragma unroll
        for (int nt = 0; nt < 4; ++nt) acc[mi][nt] = 0;

    for (int kc = 0; kc < 4; ++kc) {
        __syncthreads();
        for (int i = tid; i < 128 * 16; i += 256) {
            int r = i >> 4, d8 = (i & 15) * 8;
            *(short8*)(mb + r * 136 + d8) =
                *(const short8*)(merged + (size_t)(r0 + r) * 512 + kc * 128 + d8);
        }
        for (int i = tid; i < 64 * 16; i += 256) {
            int r = i >> 4, d8 = (i & 15) * 8;
            const float* s = Wo + (size_t)r * 512 + kc * 128 + d8;
            float4 x0 = *(const float4*)s, x1 = *(const float4*)(s + 4);
            us4 lo, hi;
            lo[0]=f2bf(x0.x); lo[1]=f2bf(x0.y); lo[2]=f2bf(x0.z); lo[3]=f2bf(x0.w);
            hi[0]=f2bf(x1.x); hi[1]=f2bf(x1.y); hi[2]=f2bf(x1.z); hi[3]=f2bf(x1.w);
            *(us4*)(wob + r * 136 + d8)     = lo;
            *(us4*)(wob + r * 136 + d8 + 4) = hi;
        }
        __syncthreads();
        #pragma unroll
        for (int mi = 0; mi < 2; ++mi) {
            const int mt = w * 2 + mi;
            #pragma unroll
            for (int ks = 0; ks < 4; ++ks) {
                short8 a = *(const short8*)(mb + (mt * 16 + c) * 136 + ks * 32 + g * 8);
                #pragma unroll
                for (int nt = 0; nt < 4; ++nt) {
                    short8 b = *(const short8*)(wob + (nt * 16 + c) * 136 + ks * 32 + g * 8);
                    acc[mi][nt] = MFMA16(a, b, acc[mi][nt]);
                }
            }
        }
    }
    #pragma unroll
    for (int mi = 0; mi < 2; ++mi) {
        const int mt = w * 2 + mi;
        #pragma unroll
        for (int nt = 0; nt < 4; ++nt) {
            const float bv2 = bo[nt * 16 + c];
            #pragma unroll
            for (int r = 0; r < 4; ++r) {
                int rg = r0 + mt * 16 + g * 4 + r;
                int bb = rg >> 11, t = rg & (T_LEN - 1);
                out[((size_t)t * BSZ + bb) * 64 + nt * 16 + c] = acc[mi][nt][r] + bv2;
            }
        }
    }
}

extern "C" void kernel_launch(void* const* d_in, const int* in_sizes, int n_in,
                              void* d_out, int out_size, void* d_ws, size_t ws_size,
                              hipStream_t stream)
{
    (void)in_sizes; (void)n_in; (void)out_size; (void)ws_size;
    const float* qin  = (const float*)d_in[0];
    const float* kin  = (const float*)d_in[1];
    const float* vin  = (const float*)d_in[2];
    const float* Wq   = (const float*)d_in[3];
    const float* bq   = (const float*)d_in[4];
    const float* Wk   = (const float*)d_in[5];
    const float* bk   = (const float*)d_in[6];
    const float* Wv   = (const float*)d_in[7];
    const float* bv   = (const float*)d_in[8];
    const float* Wo   = (const float*)d_in[9];
    const float* bo   = (const float*)d_in[10];
    const float* proj = (const float*)d_in[11];

    char* p = (char*)d_ws;
    unsigned* kmax_u = (unsigned*)p;           p += 256;
    u16* qh_ws = (u16*)p;  p += (size_t)BH * T_LEN * 64 * 2;   // 33,554,432
    u16* kh_ws = (u16*)p;  p += (size_t)BH * T_LEN * 64 * 2;
    u16* vh_ws = (u16*)p;  p += (size_t)BH * T_LEN * 64 * 2;
    float* diagq = (float*)p; p += (size_t)BH * T_LEN * 4;     // 1,048,576
    float* diagk = (float*)p; p += (size_t)BH * T_LEN * 4;
    u16* Sseg = (u16*)p;   p += (size_t)BH * NSEG * MF * 64 * 2; // 69,730,304
    u16* zseg = (u16*)p;   p += (size_t)BH * NSEG * MF * 2;      //  1,089,536
    u16* merged = (u16*)p;                                       // 33,554,432

    const int LDS_H = 27904;
    const int LDS_P = 32256;
    const int LDS_A = 80128;
    const int LDS_B = (MF * 16 + MF) * 4;
    const int LDS_C = 148224;
    const int LDS_D = 52224;
    (void)hipFuncSetAttribute((const void*)kernA, hipFuncAttributeMaxDynamicSharedMemorySize, LDS_A);
    (void)hipFuncSetAttribute((const void*)kernC, hipFuncAttributeMaxDynamicSharedMemorySize, LDS_C);

    kernInit<<<1, 64, 0, stream>>>(kmax_u);
    kernH<<<dim3(256, 3), 256, LDS_H, stream>>>(qin, kin, vin, Wq, bq, Wk, bk, Wv, bv,
                                                qh_ws, kh_ws, vh_ws, diagq, diagk);
    kernP<<<dim3(BH, NSEG), 256, LDS_P, stream>>>(kh_ws, proj, kmax_u);
    kernA<<<dim3(BH, NSEG), 512, LDS_A, stream>>>(kh_ws, vh_ws, diagk, proj, kmax_u, Sseg, zseg);
    kernB<<<dim3(BH, 4), 256, LDS_B, stream>>>(Sseg, zseg);
    kernC<<<dim3(BH, NSEG), 512, LDS_C, stream>>>(qh_ws, kh_ws, vh_ws, diagq, diagk, proj,
                                                  Sseg, zseg, kmax_u, merged);
    kernD<<<256, 256, LDS_D, stream>>>(merged, Wo, bo, out_size ? (float*)d_out : (float*)d_out);
}